// Round 13
// baseline (409.002 us; speedup 1.0000x reference)
//
#include <hip/hip_runtime.h>

constexpr int Bn  = 16;
constexpr int Tn  = 512;
constexpr int Dn  = 512;
constexpr int Hn  = 16;
constexpr int DHn = 32;
constexpr int Pn  = 1023;   // 2T-1
constexpr size_t wE = (size_t)Dn * Dn;
constexpr size_t qkvE = (size_t)Bn * Tn * Dn;       // 4,194,304
constexpr size_t posE = (size_t)Bn * Pn * Dn;       // 8,380,416

typedef __attribute__((ext_vector_type(8))) short s16x8;
typedef __attribute__((ext_vector_type(4))) float f32x4;

__device__ __forceinline__ unsigned short f2bf(float x) {
    unsigned u = __float_as_uint(x);
    unsigned r = u + 0x7fff + ((u >> 16) & 1);
    return (unsigned short)(r >> 16);
}
__device__ __forceinline__ float bf2f(unsigned short h) {
    return __uint_as_float(((unsigned)h) << 16);
}

__device__ __forceinline__ f32x4 mfma3(s16x8 ah, s16x8 al, s16x8 bh2, s16x8 bl, f32x4 c) {
    c = __builtin_amdgcn_mfma_f32_16x16x32_bf16(ah, bh2, c, 0, 0, 0);
    c = __builtin_amdgcn_mfma_f32_16x16x32_bf16(ah, bl,  c, 0, 0, 0);
    c = __builtin_amdgcn_mfma_f32_16x16x32_bf16(al, bh2, c, 0, 0, 0);
    return c;
}

// ---------------------------------------------------------------------------
// Split all 5 weight matrices (512x512 each) in one dispatch. grid (64, 5).
// ---------------------------------------------------------------------------
__global__ __launch_bounds__(256) void split_weights_kernel(
    const float* __restrict__ w0, const float* __restrict__ w1,
    const float* __restrict__ w2, const float* __restrict__ w3,
    const float* __restrict__ w4,
    unsigned short* __restrict__ hi, unsigned short* __restrict__ lo) {
    const float* srcs[5] = {w0, w1, w2, w3, w4};
    const float* src = srcs[blockIdx.y];
    const size_t off = (size_t)blockIdx.y * wE;
    unsigned short* h = hi + off;
    unsigned short* l = lo + off;
    const int n4 = Dn * Dn / 4;
    for (int i = blockIdx.x * 256 + threadIdx.x; i < n4; i += 64 * 256) {
        float4 v = ((const float4*)src)[i];
        ushort4 hh, ll;
        hh.x = f2bf(v.x); ll.x = f2bf(v.x - bf2f(hh.x));
        hh.y = f2bf(v.y); ll.y = f2bf(v.y - bf2f(hh.y));
        hh.z = f2bf(v.z); ll.z = f2bf(v.z - bf2f(hh.z));
        hh.w = f2bf(v.w); ll.w = f2bf(v.w - bf2f(hh.w));
        ((ushort4*)h)[i] = hh;
        ((ushort4*)l)[i] = ll;
    }
}

// ---------------------------------------------------------------------------
// Pre-split activations q/k/v/pos -> bf16 hi/lo planes. grid (256, 4).
// act layout: [q_hi q_lo k_hi k_lo v_hi v_lo](qkvE each) [p_hi p_lo](posE).
// ---------------------------------------------------------------------------
__global__ __launch_bounds__(256) void split_acts_kernel(
    const float* __restrict__ q, const float* __restrict__ k,
    const float* __restrict__ v, const float* __restrict__ p,
    unsigned short* __restrict__ act) {
    const int y = blockIdx.y;
    const float* src;
    unsigned short *h, *l;
    int n4;
    if (y == 0)      { src = q; h = act;            l = act + qkvE;     n4 = (int)(qkvE / 4); }
    else if (y == 1) { src = k; h = act + 2 * qkvE; l = act + 3 * qkvE; n4 = (int)(qkvE / 4); }
    else if (y == 2) { src = v; h = act + 4 * qkvE; l = act + 5 * qkvE; n4 = (int)(qkvE / 4); }
    else             { src = p; h = act + 6 * qkvE; l = h + posE;       n4 = (int)(posE / 4); }
    for (int i = blockIdx.x * 256 + threadIdx.x; i < n4; i += 256 * 256) {
        float4 vv = ((const float4*)src)[i];
        ushort4 hh, ll;
        hh.x = f2bf(vv.x); ll.x = f2bf(vv.x - bf2f(hh.x));
        hh.y = f2bf(vv.y); ll.y = f2bf(vv.y - bf2f(hh.y));
        hh.z = f2bf(vv.z); ll.z = f2bf(vv.z - bf2f(hh.z));
        hh.w = f2bf(vv.w); ll.w = f2bf(vv.w - bf2f(hh.w));
        ((ushort4*)h)[i] = hh;
        ((ushort4*)l)[i] = ll;
    }
}

// ---------------------------------------------------------------------------
// Shared-memory overlays for the fused phase-1 kernel.
// ---------------------------------------------------------------------------
struct GemmSmem {
    unsigned short AhT[128 * 40];
    unsigned short AlT[128 * 40];
    unsigned short WhT[128 * 40];
    unsigned short WlT[128 * 40];
};                                          // 40960 B
struct ConvSmem {
    float inb[68][72];
    float h1[66][76];                       // stride 76: 2-way banks (vs 4-way @72)
    float w1s[16][9], w2s[16][9], b1s[16];
};                                          // 40864 B
static_assert(sizeof(ConvSmem) <= sizeof(GemmSmem), "arena too small");

// ---------------------------------------------------------------------------
// Split-bf16 MFMA GEMM body. out = A @ W^T (+bias).
// PS=true: A pre-split bf16 planes (Agh/Agl). PS=false: A f32, split on fly.
// W pre-split planes, staged in LDS. Tile 128 x NT, BK=32, 4 waves.
// mode 0: f32 [M,512]; mode 1: f32 scatter [b,h,t,d];
// mode 2: bf16 planes [b,h,t,d]; mode 3: bf16 planes [b,h,d,t].
// ---------------------------------------------------------------------------
template<int NT, bool PS>
__device__ __forceinline__ void gemm_body(
    unsigned short* __restrict__ AhT, unsigned short* __restrict__ AlT,
    unsigned short* __restrict__ WhT, unsigned short* __restrict__ WlT,
    const float* __restrict__ A,
    const unsigned short* __restrict__ Agh, const unsigned short* __restrict__ Agl,
    const unsigned short* __restrict__ Wh, const unsigned short* __restrict__ Wl,
    const float* __restrict__ bias, float* __restrict__ outf,
    unsigned short* __restrict__ out_hi, unsigned short* __restrict__ out_lo,
    int M, int L, int mode, int nbase, int mbase) {
    constexpr int K = 512, BK = 32, LDT = 40, NW = NT / 32;
    constexpr int WC = (NT * BK) / (256 * 8);   // W chunks per thread (2 or 1)
    const int tid = threadIdx.x;
    const int wave = tid >> 6, lane = tid & 63;
    const int wr = wave >> 1, wc = wave & 1;
    const int lg = lane >> 4, lr = lane & 15;
    f32x4 acc[4][NW] = {};

    float4 pa0[2], pa1[2];
    s16x8 pah[2], pal[2];
    s16x8 pwh[WC], pwl[WC];
    auto issue_loads = [&](int k0) {
#pragma unroll
        for (int c = 0; c < 2; ++c) {
            const int cid = tid + 256 * c;         // 512 A-chunks: 128 rows x 4
            const int row = cid >> 2, col8 = (cid & 3) * 8;
            int gm = mbase + row; if (gm >= M) gm = M - 1;
            const size_t ga = (size_t)gm * K + k0 + col8;
            if (PS) {
                pah[c] = *(const s16x8*)&Agh[ga];
                pal[c] = *(const s16x8*)&Agl[ga];
            } else {
                const float* ap = A + ga;
                pa0[c] = *(const float4*)ap;
                pa1[c] = *(const float4*)(ap + 4);
            }
        }
#pragma unroll
        for (int c = 0; c < WC; ++c) {
            const int cid = tid + 256 * c;         // NT*4 W-chunks
            const int row = cid >> 2, col8 = (cid & 3) * 8;
            const size_t gw = (size_t)(nbase + row) * K + k0 + col8;
            pwh[c] = *(const s16x8*)&Wh[gw];
            pwl[c] = *(const s16x8*)&Wl[gw];
        }
    };
    issue_loads(0);
    for (int ks = 0; ks < K / BK; ++ks) {
        const int k0 = ks * BK;
        __syncthreads();   // frag reads of previous step complete
#pragma unroll
        for (int c = 0; c < 2; ++c) {
            const int cid = tid + 256 * c;
            const int loff = (cid >> 2) * LDT + (cid & 3) * 8;
            if (PS) {
                *(s16x8*)&AhT[loff] = pah[c];
                *(s16x8*)&AlT[loff] = pal[c];
            } else {
                float av[8] = {pa0[c].x, pa0[c].y, pa0[c].z, pa0[c].w,
                               pa1[c].x, pa1[c].y, pa1[c].z, pa1[c].w};
                s16x8 hh, ll;
#pragma unroll
                for (int j = 0; j < 8; ++j) {
                    unsigned short x = f2bf(av[j]);
                    hh[j] = (short)x;
                    ll[j] = (short)f2bf(av[j] - bf2f(x));
                }
                *(s16x8*)&AhT[loff] = hh;
                *(s16x8*)&AlT[loff] = ll;
            }
        }
#pragma unroll
        for (int c = 0; c < WC; ++c) {
            const int cid = tid + 256 * c;
            const int loff = (cid >> 2) * LDT + (cid & 3) * 8;
            *(s16x8*)&WhT[loff] = pwh[c];
            *(s16x8*)&WlT[loff] = pwl[c];
        }
        if (ks < K / BK - 1) issue_loads(k0 + BK);
        __syncthreads();
        s16x8 wh[NW], wl[NW];
#pragma unroll
        for (int nj = 0; nj < NW; ++nj) {
            const int off = (wc * (NT / 2) + nj * 16 + lr) * LDT + lg * 8;
            wh[nj] = *(const s16x8*)&WhT[off];
            wl[nj] = *(const s16x8*)&WlT[off];
        }
#pragma unroll
        for (int mi = 0; mi < 4; ++mi) {
            const int off = (wr * 64 + mi * 16 + lr) * LDT + lg * 8;
            s16x8 ah = *(const s16x8*)&AhT[off];
            s16x8 al = *(const s16x8*)&AlT[off];
#pragma unroll
            for (int nj = 0; nj < NW; ++nj)
                acc[mi][nj] = __builtin_amdgcn_mfma_f32_16x16x32_bf16(ah, wh[nj], acc[mi][nj], 0, 0, 0);
#pragma unroll
            for (int nj = 0; nj < NW; ++nj)
                acc[mi][nj] = __builtin_amdgcn_mfma_f32_16x16x32_bf16(ah, wl[nj], acc[mi][nj], 0, 0, 0);
#pragma unroll
            for (int nj = 0; nj < NW; ++nj)
                acc[mi][nj] = __builtin_amdgcn_mfma_f32_16x16x32_bf16(al, wh[nj], acc[mi][nj], 0, 0, 0);
        }
    }
#pragma unroll
    for (int nj = 0; nj < NW; ++nj) {
        const int n = nbase + wc * (NT / 2) + nj * 16 + lr;
        const float bv = bias ? bias[n] : 0.0f;
#pragma unroll
        for (int mi = 0; mi < 4; ++mi) {
#pragma unroll
            for (int r2 = 0; r2 < 4; ++r2) {
                const int m = mbase + wr * 64 + mi * 16 + lg * 4 + r2;
                if (m < M) {
                    const float v = acc[mi][nj][r2] + bv;
                    if (mode == 0) {
                        outf[(size_t)m * 512 + n] = v;
                    } else if (mode == 1) {
                        int bb = m / L, t = m - bb * L;
                        int hh2 = n >> 5, d = n & 31;
                        outf[(((size_t)bb * Hn + hh2) * L + t) * DHn + d] = v;
                    } else {
                        int bb = m / L, t = m - bb * L;
                        int hh2 = n >> 5, d = n & 31;
                        size_t oidx = (mode == 2)
                            ? ((((size_t)bb * Hn + hh2) * L + t) * DHn + d)
                            : ((((size_t)bb * Hn + hh2) * DHn + d) * L + t);
                        unsigned short hi16 = f2bf(v);
                        out_hi[oidx] = hi16;
                        out_lo[oidx] = f2bf(v - bf2f(hi16));
                    }
                }
            }
        }
    }
}

// ---------------------------------------------------------------------------
// Fused phase-1: blocks [0,1280) = Q/K/V/P projections (XCD-swizzled);
// blocks [1280,2304) = conv bias tiles; block 2304 = mask decode.
// ---------------------------------------------------------------------------
template<bool PS>
__global__ __launch_bounds__(256, 3) void phase1_kernel(
    const float* __restrict__ q, const float* __restrict__ k,
    const float* __restrict__ v, const float* __restrict__ p,
    const unsigned short* __restrict__ act,
    const unsigned short* __restrict__ wall_hi, const unsigned short* __restrict__ wall_lo,
    const float* __restrict__ bq, const float* __restrict__ bk,
    const float* __restrict__ bv,
    float* __restrict__ q_ws,
    unsigned short* __restrict__ k_hi, unsigned short* __restrict__ k_lo,
    unsigned short* __restrict__ v_hi, unsigned short* __restrict__ v_lo,
    unsigned short* __restrict__ p_hi, unsigned short* __restrict__ p_lo,
    const float* __restrict__ bpp, const float* __restrict__ c1w,
    const float* __restrict__ c1b, const float* __restrict__ c2w,
    const float* __restrict__ c2b, unsigned short* __restrict__ biasout,
    const unsigned char* __restrict__ mraw, float* __restrict__ mout) {
    __shared__ __align__(16) char arena[sizeof(GemmSmem)];
    const int bid = blockIdx.x;
    const int tid = threadIdx.x;

    if (bid < 1280) {
        // ---------------- Q/K/V/P projection path ----------------
        GemmSmem* gs = (GemmSmem*)arena;
        const int swz = (bid & 7) * 160 + (bid >> 3);   // 1280 = 8*160, bijective
        int z, mblk, nblk;
        if (swz < 768) { z = swz >> 8; const int r = swz & 255; mblk = r >> 2; nblk = r & 3; }
        else           { z = 3; const int r = swz - 768;        mblk = r >> 2; nblk = r & 3; }
        const float* A; const float* bias = nullptr;
        const unsigned short *agh = nullptr, *agl = nullptr;
        float* outf = nullptr; unsigned short *ohi = nullptr, *olo = nullptr;
        int M, L, mode;
        if (z == 0)      { A = q; agh = act;            agl = act + qkvE;     bias = bq; outf = q_ws; M = Bn * Tn; L = Tn; mode = 1; }
        else if (z == 1) { A = k; agh = act + 2 * qkvE; agl = act + 3 * qkvE; bias = bk; ohi = k_hi; olo = k_lo; M = Bn * Tn; L = Tn; mode = 2; }
        else if (z == 2) { A = v; agh = act + 4 * qkvE; agl = act + 5 * qkvE; bias = bv; ohi = v_hi; olo = v_lo; M = Bn * Tn; L = Tn; mode = 3; }
        else             { A = p; agh = act + 6 * qkvE; agl = agh + posE;     ohi = p_hi; olo = p_lo; M = Bn * Pn; L = Pn; mode = 2; }
        gemm_body<128, PS>(gs->AhT, gs->AlT, gs->WhT, gs->WlT,
                           A, agh, agl,
                           wall_hi + (size_t)z * wE, wall_lo + (size_t)z * wE, bias,
                           outf, ohi, olo, M, L, mode, nblk * 128, mblk * 128);
        return;
    }
    if (bid < 1280 + 1024) {
        // ---------------- conv-bias path ----------------
        ConvSmem* cs = (ConvSmem*)arena;
        const int cid = bid - 1280;
        const int b = cid >> 6, rem = cid & 63;
        const int x0 = (rem & 7) * 64, y0 = (rem >> 3) * 64;
        const int tx = tid & 15, ty = tid >> 4;

        if (tid < 144) { cs->w1s[tid / 9][tid % 9] = c1w[tid]; cs->w2s[tid / 9][tid % 9] = c2w[tid]; }
        if (tid < 16) cs->b1s[tid] = c1b[tid];
        const float* src = bpp + (size_t)b * Tn * Tn;
        for (int i = tid; i < 68 * 18; i += 256) {
            const int r = i / 18, cq = i % 18;
            const int gy = y0 - 2 + r, gx = x0 - 4 + cq * 4;
            float4 vv = make_float4(0.f, 0.f, 0.f, 0.f);
            if (gy >= 0 && gy < Tn && gx >= 0 && gx < Tn)
                vv = *(const float4*)(src + (size_t)gy * Tn + gx);
            *(float4*)&cs->inb[r][cq * 4] = vv;
        }
        __syncthreads();

        float acc[4][4] = {};
        for (int ch = 0; ch < 16; ++ch) {
            if (ch) __syncthreads();
            float w1r[9], w2r[9];
#pragma unroll
            for (int kk = 0; kk < 9; ++kk) { w1r[kk] = cs->w1s[ch][kk]; w2r[kk] = cs->w2s[ch][kk]; }
            const float b1v = cs->b1s[ch];
            for (int i = tid; i < 66 * 17; i += 256) {
                const int rr = i / 17, qq = i % 17;
                float vv[3][8];
#pragma unroll
                for (int dy = 0; dy < 3; ++dy) {
                    float4 p0 = *(const float4*)&cs->inb[rr + dy][qq * 4];
                    float4 p1 = *(const float4*)&cs->inb[rr + dy][qq * 4 + 4];
                    vv[dy][0] = p0.x; vv[dy][1] = p0.y; vv[dy][2] = p0.z; vv[dy][3] = p0.w;
                    vv[dy][4] = p1.x; vv[dy][5] = p1.y; vv[dy][6] = p1.z; vv[dy][7] = p1.w;
                }
                const int gy = y0 + rr - 1;
                const int gxb = x0 + qq * 4 - 1;
                const bool rowok = (gy >= 0 && gy < Tn);
                float o4[4];
#pragma unroll
                for (int j = 0; j < 4; ++j) {
                    float s = b1v;
#pragma unroll
                    for (int dy = 0; dy < 3; ++dy)
#pragma unroll
                        for (int dx = 0; dx < 3; ++dx)
                            s += vv[dy][2 + j + dx] * w1r[dy * 3 + dx];
                    const int gx = gxb + j;
                    o4[j] = (rowok && gx >= 0 && gx < Tn) ? fmaxf(s, 0.0f) : 0.0f;
                }
                *(float4*)&cs->h1[rr][qq * 4] = make_float4(o4[0], o4[1], o4[2], o4[3]);
            }
            __syncthreads();
            float hh[6][6];
#pragma unroll
            for (int r6 = 0; r6 < 6; ++r6) {
                float4 a = *(const float4*)&cs->h1[ty * 4 + r6][tx * 4];
                float2 b2 = *(const float2*)&cs->h1[ty * 4 + r6][tx * 4 + 4];
                hh[r6][0] = a.x; hh[r6][1] = a.y; hh[r6][2] = a.z; hh[r6][3] = a.w;
                hh[r6][4] = b2.x; hh[r6][5] = b2.y;
            }
#pragma unroll
            for (int i2 = 0; i2 < 4; ++i2)
#pragma unroll
                for (int j = 0; j < 4; ++j) {
                    float s = 0.0f;
#pragma unroll
                    for (int dy = 0; dy < 3; ++dy)
#pragma unroll
                        for (int dx = 0; dx < 3; ++dx)
                            s += hh[i2 + dy][j + dx] * w2r[dy * 3 + dx];
                    acc[i2][j] += s;
                }
        }
        const float ob = c2b[0];
#pragma unroll
        for (int i2 = 0; i2 < 4; ++i2) {
            ushort4 o;
            o.x = f2bf(acc[i2][0] + ob); o.y = f2bf(acc[i2][1] + ob);
            o.z = f2bf(acc[i2][2] + ob); o.w = f2bf(acc[i2][3] + ob);
            *(ushort4*)(biasout + ((size_t)b * Tn + y0 + ty * 4 + i2) * Tn + x0 + tx * 4) = o;
        }
        return;
    }
    // ---------------- mask-decode path (single block) ----------------
    {
        int* flags = (int*)arena;   // flags[0]=nonmod4, flags[1]=big
        if (tid == 0) { flags[0] = 0; flags[1] = 0; }
        __syncthreads();
        int f0 = 0, f1 = 0;
        for (int i = tid; i < Bn * Tn; i += 256) {
            unsigned char vv = mraw[i];
            if ((i & 3) != 0 && vv != 0) f0 = 1;
            if (vv > 1) f1 = 1;
        }
        if (f0) atomicOr(&flags[0], 1);
        if (f1) atomicOr(&flags[1], 1);
        __syncthreads();
        const int layout = flags[1] ? 2 : (flags[0] ? 1 : 0);
        for (int i = tid; i < Bn * Tn; i += 256) {
            bool m;
            if (layout == 2)      m = ((const float*)mraw)[i] != 0.0f;
            else if (layout == 1) m = mraw[i] != 0;
            else                  m = ((const int*)mraw)[i] != 0;
            mout[i] = m ? 1.0f : 0.0f;
        }
    }
}

// Output projection: 1-D grid 512 (64 m-blocks x 8 n-blocks of 64), XCD-chunked.
__global__ __launch_bounds__(256, 3) void gemm_o_kernel(
    const float* __restrict__ A,
    const unsigned short* __restrict__ Wh, const unsigned short* __restrict__ Wl,
    const float* __restrict__ bias, float* __restrict__ out) {
    constexpr int LDT = 40;
    __shared__ __align__(16) unsigned short AhT[128 * LDT];
    __shared__ __align__(16) unsigned short AlT[128 * LDT];
    __shared__ __align__(16) unsigned short WhT[64 * LDT];
    __shared__ __align__(16) unsigned short WlT[64 * LDT];
    const int bid = blockIdx.x;
    const int swz = (bid & 7) * 64 + (bid >> 3);   // 512 = 8 * 64, bijective
    const int nbase = (swz & 7) * 64;
    const int mbase = (swz >> 3) * 128;
    gemm_body<64, false>(AhT, AlT, WhT, WlT, A, nullptr, nullptr, Wh, Wl, bias,
                         out, nullptr, nullptr, Bn * Tn, Tn, 0, nbase, mbase);
}

// ---------------------------------------------------------------------------
// MFMA fused attention. 1D grid 4096 with XCD-chunked swizzle. 4 waves.
// launch_bounds(256,2): register budget must cover ~116 live regs (3 and 4
// waves/EU both force spills -> 3x slower; measured R8/R9).
// Wave-private staging -> no barriers in score/PV path.
// ---------------------------------------------------------------------------
__global__ __launch_bounds__(256, 2) void attn_mfma_kernel(
    const float* __restrict__ q_ws,
    const unsigned short* __restrict__ k_hi, const unsigned short* __restrict__ k_lo,
    const unsigned short* __restrict__ vt_hi, const unsigned short* __restrict__ vt_lo,
    const unsigned short* __restrict__ p_hi, const unsigned short* __restrict__ p_lo,
    const unsigned short* __restrict__ biasw, const float* __restrict__ maskw,
    const float* __restrict__ ub, const float* __restrict__ vb,
    float* __restrict__ ctx) {
    const int bid = blockIdx.x;
    const int wg = ((bid & 7) << 9) | (bid >> 3);
    const int t0 = (wg & 15) * 32;
    const int h = (wg >> 4) & 15;
    const int b = wg >> 8;
    const int tid = threadIdx.x;
    const int w = tid >> 6, l = tid & 63;
    const int lr = l & 15, lg = l >> 4;
    const size_t bh = (size_t)b * Hn + h;
    const int pbase = 480 - t0;
    const float scale = 0.17677669529663687f;  // 1/sqrt(32)

    __shared__ __align__(16) char uni[4][8192];
    __shared__ float redbuf[2][32][4];
    char* ubase = uni[w];

    s16x8 quh[2], qul[2], qvh[2], qvl[2];
#pragma unroll
    for (int i = 0; i < 2; ++i) {
        const float* qrow = q_ws + (bh * Tn + t0 + 16 * i + lr) * DHn + lg * 8;
        float4 qa = *(const float4*)qrow;
        float4 qb = *(const float4*)(qrow + 4);
        float qv8[8] = {qa.x, qa.y, qa.z, qa.w, qb.x, qb.y, qb.z, qb.w};
#pragma unroll
        for (int j = 0; j < 8; ++j) {
            const float uj = ub[h * DHn + lg * 8 + j];
            const float vj = vb[h * DHn + lg * 8 + j];
            float xu = qv8[j] + uj;
            unsigned short hu = f2bf(xu);
            quh[i][j] = (short)hu; qul[i][j] = (short)f2bf(xu - bf2f(hu));
            float xv = qv8[j] + vj;
            unsigned short hv = f2bf(xv);
            qvh[i][j] = (short)hv; qvl[i][j] = (short)f2bf(xv - bf2f(hv));
        }
    }
    float mv[8];
#pragma unroll
    for (int m = 0; m < 8; ++m)
        mv[m] = maskw[b * Tn + w * 128 + m * 16 + lr];

    auto posTile = [&](int i, int jt) -> f32x4 {
        int pidx = pbase + w * 128 + jt * 16 + lr;
        if (pidx > Pn - 1) pidx = Pn - 1;
        const size_t po = (bh * Pn + pidx) * DHn + lg * 8;
        s16x8 ph = *(const s16x8*)(p_hi + po);
        s16x8 pl = *(const s16x8*)(p_lo + po);
        f32x4 t = {0.f, 0.f, 0.f, 0.f};
        return mfma3(qvh[i], qvl[i], ph, pl, t);
    };

    f32x4 sc[2][8];
    f32x4 p0a = posTile(0, 1);
    f32x4 p1a = posTile(1, 0);
    const int ubb = lr - 4 * lg + 31;

#pragma unroll
    for (int m = 0; m < 8; ++m) {
        f32x4 p0b = posTile(0, m + 2);
        f32x4 p1b = posTile(1, m + 1);
        float bvls[2][4];
#pragma unroll
        for (int i2 = 0; i2 < 2; ++i2)
#pragma unroll
            for (int r2 = 0; r2 < 4; ++r2)
                bvls[i2][r2] = bf2f(biasw[((size_t)b * Tn + t0 + 16 * i2 + 4 * lg + r2) * Tn
                                          + w * 128 + m * 16 + lr]);
        const size_t ko = (bh * Tn + w * 128 + m * 16 + lr) * DHn + lg * 8;
        s16x8 kh = *(const s16x8*)(k_hi + ko);
        s16x8 kl = *(const s16x8*)(k_lo + ko);
#pragma unroll
        for (int i = 0; i < 2; ++i) {
            f32x4 c = {0.f, 0.f, 0.f, 0.f};
            c = mfma3(quh[i], qul[i], kh, kl, c);
            f32x4 Pa = (i == 0) ? p0a : p1a;
            f32x4 Pb = (i == 0) ? p0b : p1b;
            f32x4 out;
#pragma unroll
            for (int r2 = 0; r2 < 4; ++r2) {
                const int u = ubb - r2;
                const int src = (l & 48) | (u & 15);
                float pa = __shfl(Pa[r2], src, 64);
                float pb = __shfl(Pb[r2], src, 64);
                float pv = (u < 32) ? pa : pb;
                float v = (c[r2] + pv) * scale + bvls[i][r2];
                if (mv[m] != 0.0f) v = -10000.0f;
                out[r2] = v;
            }
            sc[i][m] = out;
        }
        p0a = p0b; p1a = p1b;
    }

    float rowm[2][4], inv[2][4];
#pragma unroll
    for (int i = 0; i < 2; ++i)
#pragma unroll
        for (int r2 = 0; r2 < 4; ++r2) {
            float mx = -1e30f;
#pragma unroll
            for (int m = 0; m < 8; ++m) mx = fmaxf(mx, sc[i][m][r2]);
#pragma unroll
            for (int off = 1; off < 16; off <<= 1) mx = fmaxf(mx, __shfl_xor(mx, off, 64));
            if (lr == 0) redbuf[0][16 * i + 4 * lg + r2][w] = mx;
        }
    __syncthreads();
#pragma unroll
    for (int i = 0; i < 2; ++i)
#pragma unroll
        for (int r2 = 0; r2 < 4; ++r2) {
            float4 mm = *(const float4*)redbuf[0][16 * i + 4 * lg + r2];
            rowm[i][r2] = fmaxf(fmaxf(mm.x, mm.y), fmaxf(mm.z, mm.w));
        }
    float psum[2][4] = {};
#pragma unroll
    for (int i = 0; i < 2; ++i)
#pragma unroll
        for (int m = 0; m < 8; ++m)
#pragma unroll
            for (int r2 = 0; r2 < 4; ++r2) {
                float e = __expf(sc[i][m][r2] - rowm[i][r2]);
                sc[i][m][r2] = e;
                psum[i][r2] += e;
            }
#pragma unroll
    for (int i = 0; i < 2; ++i)
#pragma unroll
        for (int r2 = 0; r2 < 4; ++r2) {
            float s = psum[i][r2];
#pragma unroll
            for (int off = 1; off < 16; off <<= 1) s += __shfl_xor(s, off, 64);
            if (lr == 0) redbuf[1][16 * i + 4 * lg + r2][w] = s;
        }
    __syncthreads();
#pragma unroll
    for (int i = 0; i < 2; ++i)
#pragma unroll
        for (int r2 = 0; r2 < 4; ++r2) {
            float4 ss = *(const float4*)redbuf[1][16 * i + 4 * lg + r2];
            inv[i][r2] = 1.0f / (ss.x + ss.y + ss.z + ss.w);
        }

    // PV: staging buffers are per-wave-private -> wave-lockstep ordering,
    // no __syncthreads needed in this loop.
    f32x4 cacc[2][2] = {};
#pragma unroll
    for (int sh = 0; sh < 2; ++sh) {
#pragma unroll
        for (int mm2 = 0; mm2 < 4; ++mm2) {
            const int m = sh * 4 + mm2;
#pragma unroll
            for (int i = 0; i < 2; ++i)
#pragma unroll
                for (int r2 = 0; r2 < 4; ++r2) {
                    const int trow = 16 * i + 4 * lg + r2;
                    float a = sc[i][m][r2] * inv[i][r2];
                    unsigned short ah16 = f2bf(a);
                    unsigned short al16 = f2bf(a - bf2f(ah16));
                    const int cbyte = (mm2 * 16 + lr) * 2;
                    const int off = trow * 128 + (cbyte ^ ((trow & 7) << 4));
                    *(unsigned short*)(ubase + off) = ah16;
                    *(unsigned short*)(ubase + 4096 + off) = al16;
                }
        }
#pragma unroll
        for (int ks = 0; ks < 2; ++ks) {
            s16x8 pah[2], pal[2];
#pragma unroll
            for (int i = 0; i < 2; ++i) {
                const int trow = 16 * i + lr;
                const int cbyte = ks * 64 + lg * 16;
                const int off = trow * 128 + (cbyte ^ ((trow & 7) << 4));
                pah[i] = *(const s16x8*)(ubase + off);
                pal[i] = *(const s16x8*)(ubase + 4096 + off);
            }
#pragma unroll
            for (int n = 0; n < 2; ++n) {
                const int sg = w * 128 + sh * 64 + ks * 32 + lg * 8;
                const size_t vo = (bh * DHn + n * 16 + lr) * Tn + sg;
                s16x8 vh = *(const s16x8*)(vt_hi + vo);
                s16x8 vl = *(const s16x8*)(vt_lo + vo);
#pragma unroll
                for (int i = 0; i < 2; ++i)
                    cacc[i][n] = mfma3(pah[i], pal[i], vh, vl, cacc[i][n]);
            }
        }
    }

    // ctxred write is wave-private; single barrier before cross-wave read.
    {
        float* cr = (float*)ubase;
#pragma unroll
        for (int i = 0; i < 2; ++i)
#pragma unroll
            for (int n = 0; n < 2; ++n)
#pragma unroll
                for (int r2 = 0; r2 < 4; ++r2)
                    cr[(16 * i + 4 * lg + r2) * 36 + n * 16 + lr] = cacc[i][n][r2];
    }
    __syncthreads();
    {
        const int trow = tid >> 3, d0 = (tid & 7) * 4;
        float4 s0 = *(const float4*)((float*)uni[0] + trow * 36 + d0);
        float4 s1 = *(const float4*)((float*)uni[1] + trow * 36 + d0);
        float4 s2 = *(const float4*)((float*)uni[2] + trow * 36 + d0);
        float4 s3 = *(const float4*)((float*)uni[3] + trow * 36 + d0);
        float4 o = make_float4(s0.x + s1.x + s2.x + s3.x, s0.y + s1.y + s2.y + s3.y,
                               s0.z + s1.z + s2.z + s3.z, s0.w + s1.w + s2.w + s3.w);
        *(float4*)(ctx + ((size_t)b * Tn + t0 + trow) * Dn + h * DHn + d0) = o;
    }
}

// ---------------------------------------------------------------------------
extern "C" void kernel_launch(void* const* d_in, const int* in_sizes, int n_in,
                              void* d_out, int out_size, void* d_ws, size_t ws_size,
                              hipStream_t stream) {
    const float* query = (const float*)d_in[0];
    const float* key   = (const float*)d_in[1];
    const float* value = (const float*)d_in[2];
    const float* pos   = (const float*)d_in[3];
    const unsigned char* mask = (const unsigned char*)d_in[4];
    const float* bpp = (const float*)d_in[5];
    const float* Wq = (const float*)d_in[6];
    const float* bq = (const float*)d_in[7];
    const float* Wk = (const float*)d_in[8];
    const float* bk = (const float*)d_in[9];
    const float* Wv = (const float*)d_in[10];
    const float* bv = (const float*)d_in[11];
    const float* Wp = (const float*)d_in[12];
    const float* Wo = (const float*)d_in[13];
    const float* bo = (const float*)d_in[14];
    const float* ub = (const float*)d_in[15];
    const float* vbias = (const float*)d_in[16];
    const float* c1w = (const float*)d_in[17];
    const float* c1b = (const float*)d_in[18];
    const float* c2w = (const float*)d_in[19];
    const float* c2b = (const float*)d_in[20];

    char* wsb = (char*)d_ws;
    unsigned short* bias_ws = (unsigned short*)wsb;             // [B,T,T] bf16
    float* mask_ws = (float*)(wsb + sizeof(unsigned short) * (size_t)Bn * Tn * Tn);
    float* q_ws    = mask_ws + Bn * Tn;                          // [B,H,T,DH] f32
    float* ctx_ws  = q_ws + qkvE;                                // [B,T,D] f32
    unsigned short* k_hi = (unsigned short*)(ctx_ws + qkvE);
    unsigned short* k_lo = k_hi + qkvE;
    unsigned short* v_hi = k_lo + qkvE;                          // [B,H,DH,T]
    unsigned short* v_lo = v_hi + qkvE;
    unsigned short* p_hi = v_lo + qkvE;                          // [B,H,P,DH]
    unsigned short* p_lo = p_hi + posE;
    unsigned short* wall_hi = p_lo + posE;                       // 5 x [D,D]
    unsigned short* wall_lo = wall_hi + 5 * wE;
    unsigned short* act = wall_lo + 5 * wE;                      // pre-split acts
    const size_t needed = (size_t)((char*)(act + 6 * qkvE + 2 * posE) - wsb);
    const bool ps = ws_size >= needed;

    // weight order: 0=Wq 1=Wk 2=Wv 3=Wp 4=Wo
    split_weights_kernel<<<dim3(64, 5), dim3(256), 0, stream>>>(
        Wq, Wk, Wv, Wp, Wo, wall_hi, wall_lo);

    if (ps) {
        split_acts_kernel<<<dim3(256, 4), dim3(256), 0, stream>>>(
            query, key, value, pos, act);
        phase1_kernel<true><<<dim3(1280 + 1024 + 1), dim3(256), 0, stream>>>(
            query, key, value, pos, act, wall_hi, wall_lo, bq, bk, bv,
            q_ws, k_hi, k_lo, v_hi, v_lo, p_hi, p_lo,
            bpp, c1w, c1b, c2w, c2b, bias_ws, mask, mask_ws);
    } else {
        phase1_kernel<false><<<dim3(1280 + 1024 + 1), dim3(256), 0, stream>>>(
            query, key, value, pos, act, wall_hi, wall_lo, bq, bk, bv,
            q_ws, k_hi, k_lo, v_hi, v_lo, p_hi, p_lo,
            bpp, c1w, c1b, c2w, c2b, bias_ws, mask, mask_ws);
    }

    attn_mfma_kernel<<<dim3(4096), dim3(256), 0, stream>>>(
        q_ws, k_hi, k_lo, v_hi, v_lo, p_hi, p_lo, bias_ws, mask_ws, ub, vbias, ctx_ws);

    gemm_o_kernel<<<dim3(512), dim3(256), 0, stream>>>(
        ctx_ws, wall_hi + 4 * wE, wall_lo + 4 * wE, bo, (float*)d_out);
}

// Round 14
// 364.257 us; speedup vs baseline: 1.1228x; 1.1228x over previous
//
#include <hip/hip_runtime.h>

constexpr int Bn  = 16;
constexpr int Tn  = 512;
constexpr int Dn  = 512;
constexpr int Hn  = 16;
constexpr int DHn = 32;
constexpr int Pn  = 1023;   // 2T-1
constexpr size_t wE = (size_t)Dn * Dn;
constexpr size_t qkvE = (size_t)Bn * Tn * Dn;       // 4,194,304
constexpr size_t posE = (size_t)Bn * Pn * Dn;       // 8,380,416

typedef __attribute__((ext_vector_type(8))) short s16x8;
typedef __attribute__((ext_vector_type(4))) float f32x4;

__device__ __forceinline__ unsigned short f2bf(float x) {
    unsigned u = __float_as_uint(x);
    unsigned r = u + 0x7fff + ((u >> 16) & 1);
    return (unsigned short)(r >> 16);
}
__device__ __forceinline__ float bf2f(unsigned short h) {
    return __uint_as_float(((unsigned)h) << 16);
}

__device__ __forceinline__ f32x4 mfma3(s16x8 ah, s16x8 al, s16x8 bh2, s16x8 bl, f32x4 c) {
    c = __builtin_amdgcn_mfma_f32_16x16x32_bf16(ah, bh2, c, 0, 0, 0);
    c = __builtin_amdgcn_mfma_f32_16x16x32_bf16(ah, bl,  c, 0, 0, 0);
    c = __builtin_amdgcn_mfma_f32_16x16x32_bf16(al, bh2, c, 0, 0, 0);
    return c;
}

// ---------------------------------------------------------------------------
// Split all 5 weight matrices (512x512 each) in one dispatch. grid (64, 5).
// ---------------------------------------------------------------------------
__global__ __launch_bounds__(256) void split_weights_kernel(
    const float* __restrict__ w0, const float* __restrict__ w1,
    const float* __restrict__ w2, const float* __restrict__ w3,
    const float* __restrict__ w4,
    unsigned short* __restrict__ hi, unsigned short* __restrict__ lo) {
    const float* srcs[5] = {w0, w1, w2, w3, w4};
    const float* src = srcs[blockIdx.y];
    const size_t off = (size_t)blockIdx.y * wE;
    unsigned short* h = hi + off;
    unsigned short* l = lo + off;
    const int n4 = Dn * Dn / 4;
    for (int i = blockIdx.x * 256 + threadIdx.x; i < n4; i += 64 * 256) {
        float4 v = ((const float4*)src)[i];
        ushort4 hh, ll;
        hh.x = f2bf(v.x); ll.x = f2bf(v.x - bf2f(hh.x));
        hh.y = f2bf(v.y); ll.y = f2bf(v.y - bf2f(hh.y));
        hh.z = f2bf(v.z); ll.z = f2bf(v.z - bf2f(hh.z));
        hh.w = f2bf(v.w); ll.w = f2bf(v.w - bf2f(hh.w));
        ((ushort4*)h)[i] = hh;
        ((ushort4*)l)[i] = ll;
    }
}

// ---------------------------------------------------------------------------
// Shared-memory overlays for the fused phase-1 kernel.
// ---------------------------------------------------------------------------
struct GemmSmem {
    unsigned short AhT[128 * 40];
    unsigned short AlT[128 * 40];
    unsigned short WhT[128 * 40];
    unsigned short WlT[128 * 40];
};                                          // 40960 B
struct ConvSmem {
    float inb[68][72];
    float h1[66][76];
    float w1s[16][9], w2s[16][9], b1s[16];
};                                          // 40864 B
static_assert(sizeof(ConvSmem) <= sizeof(GemmSmem), "arena too small");

// ---------------------------------------------------------------------------
// Split-bf16 MFMA GEMM body. out = A @ W^T (+bias). A:[M,512] f32 (split on
// the fly). W pre-split planes, staged in LDS. Tile 128 x NT, BK=32, 4 waves,
// reg-prefetch of next K-slice. LDS buffers provided by caller.
// mode 0: f32 [M,512]; mode 1: f32 scatter [b,h,t,d];
// mode 2: bf16 planes [b,h,t,d]; mode 3: bf16 planes [b,h,d,t].
// ---------------------------------------------------------------------------
template<int NT>
__device__ __forceinline__ void gemm_body(
    unsigned short* __restrict__ AhT, unsigned short* __restrict__ AlT,
    unsigned short* __restrict__ WhT, unsigned short* __restrict__ WlT,
    const float* __restrict__ A,
    const unsigned short* __restrict__ Wh, const unsigned short* __restrict__ Wl,
    const float* __restrict__ bias, float* __restrict__ outf,
    unsigned short* __restrict__ out_hi, unsigned short* __restrict__ out_lo,
    int M, int L, int mode, int nbase, int mbase) {
    constexpr int K = 512, BK = 32, LDT = 40, NW = NT / 32;
    constexpr int WC = (NT * BK) / (256 * 8);   // W chunks per thread (2 or 1)
    const int tid = threadIdx.x;
    const int wave = tid >> 6, lane = tid & 63;
    const int wr = wave >> 1, wc = wave & 1;
    const int lg = lane >> 4, lr = lane & 15;
    f32x4 acc[4][NW] = {};

    float4 pa0[2], pa1[2];
    s16x8 pwh[WC], pwl[WC];
    auto issue_loads = [&](int k0) {
#pragma unroll
        for (int c = 0; c < 2; ++c) {
            const int cid = tid + 256 * c;         // 512 A-chunks: 128 rows x 4
            const int row = cid >> 2, col8 = (cid & 3) * 8;
            int gm = mbase + row; if (gm >= M) gm = M - 1;
            const float* ap = A + (size_t)gm * K + k0 + col8;
            pa0[c] = *(const float4*)ap;
            pa1[c] = *(const float4*)(ap + 4);
        }
#pragma unroll
        for (int c = 0; c < WC; ++c) {
            const int cid = tid + 256 * c;         // NT*4 W-chunks
            const int row = cid >> 2, col8 = (cid & 3) * 8;
            const size_t gw = (size_t)(nbase + row) * K + k0 + col8;
            pwh[c] = *(const s16x8*)&Wh[gw];
            pwl[c] = *(const s16x8*)&Wl[gw];
        }
    };
    issue_loads(0);
    for (int ks = 0; ks < K / BK; ++ks) {
        const int k0 = ks * BK;
        __syncthreads();   // frag reads of previous step complete
#pragma unroll
        for (int c = 0; c < 2; ++c) {
            const int cid = tid + 256 * c;
            const int row = cid >> 2, col8 = (cid & 3) * 8;
            float av[8] = {pa0[c].x, pa0[c].y, pa0[c].z, pa0[c].w,
                           pa1[c].x, pa1[c].y, pa1[c].z, pa1[c].w};
            s16x8 hh, ll;
#pragma unroll
            for (int j = 0; j < 8; ++j) {
                unsigned short x = f2bf(av[j]);
                hh[j] = (short)x;
                ll[j] = (short)f2bf(av[j] - bf2f(x));
            }
            const int loff = row * LDT + col8;
            *(s16x8*)&AhT[loff] = hh;
            *(s16x8*)&AlT[loff] = ll;
        }
#pragma unroll
        for (int c = 0; c < WC; ++c) {
            const int cid = tid + 256 * c;
            const int loff = (cid >> 2) * LDT + (cid & 3) * 8;
            *(s16x8*)&WhT[loff] = pwh[c];
            *(s16x8*)&WlT[loff] = pwl[c];
        }
        if (ks < K / BK - 1) issue_loads(k0 + BK);
        __syncthreads();
        s16x8 wh[NW], wl[NW];
#pragma unroll
        for (int nj = 0; nj < NW; ++nj) {
            const int off = (wc * (NT / 2) + nj * 16 + lr) * LDT + lg * 8;
            wh[nj] = *(const s16x8*)&WhT[off];
            wl[nj] = *(const s16x8*)&WlT[off];
        }
#pragma unroll
        for (int mi = 0; mi < 4; ++mi) {
            const int off = (wr * 64 + mi * 16 + lr) * LDT + lg * 8;
            s16x8 ah = *(const s16x8*)&AhT[off];
            s16x8 al = *(const s16x8*)&AlT[off];
#pragma unroll
            for (int nj = 0; nj < NW; ++nj)
                acc[mi][nj] = __builtin_amdgcn_mfma_f32_16x16x32_bf16(ah, wh[nj], acc[mi][nj], 0, 0, 0);
#pragma unroll
            for (int nj = 0; nj < NW; ++nj)
                acc[mi][nj] = __builtin_amdgcn_mfma_f32_16x16x32_bf16(ah, wl[nj], acc[mi][nj], 0, 0, 0);
#pragma unroll
            for (int nj = 0; nj < NW; ++nj)
                acc[mi][nj] = __builtin_amdgcn_mfma_f32_16x16x32_bf16(al, wh[nj], acc[mi][nj], 0, 0, 0);
        }
    }
#pragma unroll
    for (int nj = 0; nj < NW; ++nj) {
        const int n = nbase + wc * (NT / 2) + nj * 16 + lr;
        const float bv = bias ? bias[n] : 0.0f;
#pragma unroll
        for (int mi = 0; mi < 4; ++mi) {
#pragma unroll
            for (int r2 = 0; r2 < 4; ++r2) {
                const int m = mbase + wr * 64 + mi * 16 + lg * 4 + r2;
                if (m < M) {
                    const float v = acc[mi][nj][r2] + bv;
                    if (mode == 0) {
                        outf[(size_t)m * 512 + n] = v;
                    } else if (mode == 1) {
                        int bb = m / L, t = m - bb * L;
                        int hh2 = n >> 5, d = n & 31;
                        outf[(((size_t)bb * Hn + hh2) * L + t) * DHn + d] = v;
                    } else {
                        int bb = m / L, t = m - bb * L;
                        int hh2 = n >> 5, d = n & 31;
                        size_t oidx = (mode == 2)
                            ? ((((size_t)bb * Hn + hh2) * L + t) * DHn + d)
                            : ((((size_t)bb * Hn + hh2) * DHn + d) * L + t);
                        unsigned short hi16 = f2bf(v);
                        out_hi[oidx] = hi16;
                        out_lo[oidx] = f2bf(v - bf2f(hi16));
                    }
                }
            }
        }
    }
}

// ---------------------------------------------------------------------------
// Fused phase-1, INTERLEAVED: period-72 blocks = 40 GEMM + 32 conv, so every
// CU co-hosts VALU-bound conv waves with MFMA/LDS-bound GEMM waves (they use
// different pipes and overlap; m114). 32 periods = 2304 blocks; +1 mask block.
// ---------------------------------------------------------------------------
__global__ __launch_bounds__(256, 3) void phase1_kernel(
    const float* __restrict__ q, const float* __restrict__ k,
    const float* __restrict__ v, const float* __restrict__ p,
    const unsigned short* __restrict__ wall_hi, const unsigned short* __restrict__ wall_lo,
    const float* __restrict__ bq, const float* __restrict__ bk,
    const float* __restrict__ bv,
    float* __restrict__ q_ws,
    unsigned short* __restrict__ k_hi, unsigned short* __restrict__ k_lo,
    unsigned short* __restrict__ v_hi, unsigned short* __restrict__ v_lo,
    unsigned short* __restrict__ p_hi, unsigned short* __restrict__ p_lo,
    const float* __restrict__ bpp, const float* __restrict__ c1w,
    const float* __restrict__ c1b, const float* __restrict__ c2w,
    const float* __restrict__ c2b, unsigned short* __restrict__ biasout,
    const unsigned char* __restrict__ mraw, float* __restrict__ mout) {
    __shared__ __align__(16) char arena[sizeof(GemmSmem)];
    const int bid = blockIdx.x;
    const int tid = threadIdx.x;

    if (bid < 2304 && (bid % 72) < 40) {
        // ---------------- Q/K/V/P projection path ----------------
        GemmSmem* gs = (GemmSmem*)arena;
        const int gid = (bid / 72) * 40 + (bid % 72);   // [0,1280) compacted
        const int swz = (gid & 7) * 160 + (gid >> 3);   // 1280 = 8*160, bijective
        int z, mblk, nblk;
        if (swz < 768) { z = swz >> 8; const int r = swz & 255; mblk = r >> 2; nblk = r & 3; }
        else           { z = 3; const int r = swz - 768;        mblk = r >> 2; nblk = r & 3; }
        const float* A; const float* bias = nullptr;
        float* outf = nullptr; unsigned short *ohi = nullptr, *olo = nullptr;
        int M, L, mode;
        if (z == 0)      { A = q; bias = bq; outf = q_ws; M = Bn * Tn; L = Tn; mode = 1; }
        else if (z == 1) { A = k; bias = bk; ohi = k_hi; olo = k_lo; M = Bn * Tn; L = Tn; mode = 2; }
        else if (z == 2) { A = v; bias = bv; ohi = v_hi; olo = v_lo; M = Bn * Tn; L = Tn; mode = 3; }
        else             { A = p; ohi = p_hi; olo = p_lo; M = Bn * Pn; L = Pn; mode = 2; }
        gemm_body<128>(gs->AhT, gs->AlT, gs->WhT, gs->WlT,
                       A, wall_hi + (size_t)z * wE, wall_lo + (size_t)z * wE, bias,
                       outf, ohi, olo, M, L, mode, nblk * 128, mblk * 128);
        return;
    }
    if (bid < 2304) {
        // ---------------- conv-bias path ----------------
        ConvSmem* cs = (ConvSmem*)arena;
        const int cid = (bid / 72) * 32 + (bid % 72 - 40);  // [0,1024) compacted
        const int b = cid >> 6, rem = cid & 63;
        const int x0 = (rem & 7) * 64, y0 = (rem >> 3) * 64;
        const int tx = tid & 15, ty = tid >> 4;

        if (tid < 144) { cs->w1s[tid / 9][tid % 9] = c1w[tid]; cs->w2s[tid / 9][tid % 9] = c2w[tid]; }
        if (tid < 16) cs->b1s[tid] = c1b[tid];
        const float* src = bpp + (size_t)b * Tn * Tn;
        for (int i = tid; i < 68 * 18; i += 256) {
            const int r = i / 18, cq = i % 18;
            const int gy = y0 - 2 + r, gx = x0 - 4 + cq * 4;
            float4 vv = make_float4(0.f, 0.f, 0.f, 0.f);
            if (gy >= 0 && gy < Tn && gx >= 0 && gx < Tn)
                vv = *(const float4*)(src + (size_t)gy * Tn + gx);
            *(float4*)&cs->inb[r][cq * 4] = vv;
        }
        __syncthreads();

        float acc[4][4] = {};
        for (int ch = 0; ch < 16; ++ch) {
            if (ch) __syncthreads();
            float w1r[9], w2r[9];
#pragma unroll
            for (int kk = 0; kk < 9; ++kk) { w1r[kk] = cs->w1s[ch][kk]; w2r[kk] = cs->w2s[ch][kk]; }
            const float b1v = cs->b1s[ch];
            for (int i = tid; i < 66 * 17; i += 256) {
                const int rr = i / 17, qq = i % 17;
                float vv[3][8];
#pragma unroll
                for (int dy = 0; dy < 3; ++dy) {
                    float4 p0 = *(const float4*)&cs->inb[rr + dy][qq * 4];
                    float4 p1 = *(const float4*)&cs->inb[rr + dy][qq * 4 + 4];
                    vv[dy][0] = p0.x; vv[dy][1] = p0.y; vv[dy][2] = p0.z; vv[dy][3] = p0.w;
                    vv[dy][4] = p1.x; vv[dy][5] = p1.y; vv[dy][6] = p1.z; vv[dy][7] = p1.w;
                }
                const int gy = y0 + rr - 1;
                const int gxb = x0 + qq * 4 - 1;
                const bool rowok = (gy >= 0 && gy < Tn);
                float o4[4];
#pragma unroll
                for (int j = 0; j < 4; ++j) {
                    float s = b1v;
#pragma unroll
                    for (int dy = 0; dy < 3; ++dy)
#pragma unroll
                        for (int dx = 0; dx < 3; ++dx)
                            s += vv[dy][2 + j + dx] * w1r[dy * 3 + dx];
                    const int gx = gxb + j;
                    o4[j] = (rowok && gx >= 0 && gx < Tn) ? fmaxf(s, 0.0f) : 0.0f;
                }
                *(float4*)&cs->h1[rr][qq * 4] = make_float4(o4[0], o4[1], o4[2], o4[3]);
            }
            __syncthreads();
            float hh[6][6];
#pragma unroll
            for (int r6 = 0; r6 < 6; ++r6) {
                float4 a = *(const float4*)&cs->h1[ty * 4 + r6][tx * 4];
                float2 b2 = *(const float2*)&cs->h1[ty * 4 + r6][tx * 4 + 4];
                hh[r6][0] = a.x; hh[r6][1] = a.y; hh[r6][2] = a.z; hh[r6][3] = a.w;
                hh[r6][4] = b2.x; hh[r6][5] = b2.y;
            }
#pragma unroll
            for (int i2 = 0; i2 < 4; ++i2)
#pragma unroll
                for (int j = 0; j < 4; ++j) {
                    float s = 0.0f;
#pragma unroll
                    for (int dy = 0; dy < 3; ++dy)
#pragma unroll
                        for (int dx = 0; dx < 3; ++dx)
                            s += hh[i2 + dy][j + dx] * w2r[dy * 3 + dx];
                    acc[i2][j] += s;
                }
        }
        const float ob = c2b[0];
#pragma unroll
        for (int i2 = 0; i2 < 4; ++i2) {
            ushort4 o;
            o.x = f2bf(acc[i2][0] + ob); o.y = f2bf(acc[i2][1] + ob);
            o.z = f2bf(acc[i2][2] + ob); o.w = f2bf(acc[i2][3] + ob);
            *(ushort4*)(biasout + ((size_t)b * Tn + y0 + ty * 4 + i2) * Tn + x0 + tx * 4) = o;
        }
        return;
    }
    // ---------------- mask-decode path (single block, bid == 2304) ----------
    {
        int* flags = (int*)arena;   // flags[0]=nonmod4, flags[1]=big
        if (tid == 0) { flags[0] = 0; flags[1] = 0; }
        __syncthreads();
        int f0 = 0, f1 = 0;
        for (int i = tid; i < Bn * Tn; i += 256) {
            unsigned char vv = mraw[i];
            if ((i & 3) != 0 && vv != 0) f0 = 1;
            if (vv > 1) f1 = 1;
        }
        if (f0) atomicOr(&flags[0], 1);
        if (f1) atomicOr(&flags[1], 1);
        __syncthreads();
        const int layout = flags[1] ? 2 : (flags[0] ? 1 : 0);
        for (int i = tid; i < Bn * Tn; i += 256) {
            bool m;
            if (layout == 2)      m = ((const float*)mraw)[i] != 0.0f;
            else if (layout == 1) m = mraw[i] != 0;
            else                  m = ((const int*)mraw)[i] != 0;
            mout[i] = m ? 1.0f : 0.0f;
        }
    }
}

// Output projection: 1-D grid 512 (64 m-blocks x 8 n-blocks of 64), XCD-chunked.
__global__ __launch_bounds__(256, 3) void gemm_o_kernel(
    const float* __restrict__ A,
    const unsigned short* __restrict__ Wh, const unsigned short* __restrict__ Wl,
    const float* __restrict__ bias, float* __restrict__ out) {
    constexpr int LDT = 40;
    __shared__ __align__(16) unsigned short AhT[128 * LDT];
    __shared__ __align__(16) unsigned short AlT[128 * LDT];
    __shared__ __align__(16) unsigned short WhT[64 * LDT];
    __shared__ __align__(16) unsigned short WlT[64 * LDT];
    const int bid = blockIdx.x;
    const int swz = (bid & 7) * 64 + (bid >> 3);   // 512 = 8 * 64, bijective
    const int nbase = (swz & 7) * 64;
    const int mbase = (swz >> 3) * 128;
    gemm_body<64>(AhT, AlT, WhT, WlT, A, Wh, Wl, bias, out, nullptr, nullptr,
                  Bn * Tn, Tn, 0, nbase, mbase);
}

// ---------------------------------------------------------------------------
// MFMA fused attention. 1D grid 4096 with XCD-chunked swizzle. 4 waves.
// launch_bounds(256,2): register budget must cover ~116 live regs (3 and 4
// waves/EU both force spills -> 3x slower; measured R8/R9).
// Wave-private staging -> no barriers in score/PV path.
// ---------------------------------------------------------------------------
__global__ __launch_bounds__(256, 2) void attn_mfma_kernel(
    const float* __restrict__ q_ws,
    const unsigned short* __restrict__ k_hi, const unsigned short* __restrict__ k_lo,
    const unsigned short* __restrict__ vt_hi, const unsigned short* __restrict__ vt_lo,
    const unsigned short* __restrict__ p_hi, const unsigned short* __restrict__ p_lo,
    const unsigned short* __restrict__ biasw, const float* __restrict__ maskw,
    const float* __restrict__ ub, const float* __restrict__ vb,
    float* __restrict__ ctx) {
    const int bid = blockIdx.x;
    const int wg = ((bid & 7) << 9) | (bid >> 3);
    const int t0 = (wg & 15) * 32;
    const int h = (wg >> 4) & 15;
    const int b = wg >> 8;
    const int tid = threadIdx.x;
    const int w = tid >> 6, l = tid & 63;
    const int lr = l & 15, lg = l >> 4;
    const size_t bh = (size_t)b * Hn + h;
    const int pbase = 480 - t0;
    const float scale = 0.17677669529663687f;  // 1/sqrt(32)

    __shared__ __align__(16) char uni[4][8192];
    __shared__ float redbuf[2][32][4];
    char* ubase = uni[w];

    s16x8 quh[2], qul[2], qvh[2], qvl[2];
#pragma unroll
    for (int i = 0; i < 2; ++i) {
        const float* qrow = q_ws + (bh * Tn + t0 + 16 * i + lr) * DHn + lg * 8;
        float4 qa = *(const float4*)qrow;
        float4 qb = *(const float4*)(qrow + 4);
        float qv8[8] = {qa.x, qa.y, qa.z, qa.w, qb.x, qb.y, qb.z, qb.w};
#pragma unroll
        for (int j = 0; j < 8; ++j) {
            const float uj = ub[h * DHn + lg * 8 + j];
            const float vj = vb[h * DHn + lg * 8 + j];
            float xu = qv8[j] + uj;
            unsigned short hu = f2bf(xu);
            quh[i][j] = (short)hu; qul[i][j] = (short)f2bf(xu - bf2f(hu));
            float xv = qv8[j] + vj;
            unsigned short hv = f2bf(xv);
            qvh[i][j] = (short)hv; qvl[i][j] = (short)f2bf(xv - bf2f(hv));
        }
    }
    float mv[8];
#pragma unroll
    for (int m = 0; m < 8; ++m)
        mv[m] = maskw[b * Tn + w * 128 + m * 16 + lr];

    auto posTile = [&](int i, int jt) -> f32x4 {
        int pidx = pbase + w * 128 + jt * 16 + lr;
        if (pidx > Pn - 1) pidx = Pn - 1;
        const size_t po = (bh * Pn + pidx) * DHn + lg * 8;
        s16x8 ph = *(const s16x8*)(p_hi + po);
        s16x8 pl = *(const s16x8*)(p_lo + po);
        f32x4 t = {0.f, 0.f, 0.f, 0.f};
        return mfma3(qvh[i], qvl[i], ph, pl, t);
    };

    f32x4 sc[2][8];
    f32x4 p0a = posTile(0, 1);
    f32x4 p1a = posTile(1, 0);
    const int ubb = lr - 4 * lg + 31;

#pragma unroll
    for (int m = 0; m < 8; ++m) {
        f32x4 p0b = posTile(0, m + 2);
        f32x4 p1b = posTile(1, m + 1);
        float bvls[2][4];
#pragma unroll
        for (int i2 = 0; i2 < 2; ++i2)
#pragma unroll
            for (int r2 = 0; r2 < 4; ++r2)
                bvls[i2][r2] = bf2f(biasw[((size_t)b * Tn + t0 + 16 * i2 + 4 * lg + r2) * Tn
                                          + w * 128 + m * 16 + lr]);
        const size_t ko = (bh * Tn + w * 128 + m * 16 + lr) * DHn + lg * 8;
        s16x8 kh = *(const s16x8*)(k_hi + ko);
        s16x8 kl = *(const s16x8*)(k_lo + ko);
#pragma unroll
        for (int i = 0; i < 2; ++i) {
            f32x4 c = {0.f, 0.f, 0.f, 0.f};
            c = mfma3(quh[i], qul[i], kh, kl, c);
            f32x4 Pa = (i == 0) ? p0a : p1a;
            f32x4 Pb = (i == 0) ? p0b : p1b;
            f32x4 out;
#pragma unroll
            for (int r2 = 0; r2 < 4; ++r2) {
                const int u = ubb - r2;
                const int src = (l & 48) | (u & 15);
                float pa = __shfl(Pa[r2], src, 64);
                float pb = __shfl(Pb[r2], src, 64);
                float pv = (u < 32) ? pa : pb;
                float v = (c[r2] + pv) * scale + bvls[i][r2];
                if (mv[m] != 0.0f) v = -10000.0f;
                out[r2] = v;
            }
            sc[i][m] = out;
        }
        p0a = p0b; p1a = p1b;
    }

    float rowm[2][4], inv[2][4];
#pragma unroll
    for (int i = 0; i < 2; ++i)
#pragma unroll
        for (int r2 = 0; r2 < 4; ++r2) {
            float mx = -1e30f;
#pragma unroll
            for (int m = 0; m < 8; ++m) mx = fmaxf(mx, sc[i][m][r2]);
#pragma unroll
            for (int off = 1; off < 16; off <<= 1) mx = fmaxf(mx, __shfl_xor(mx, off, 64));
            if (lr == 0) redbuf[0][16 * i + 4 * lg + r2][w] = mx;
        }
    __syncthreads();
#pragma unroll
    for (int i = 0; i < 2; ++i)
#pragma unroll
        for (int r2 = 0; r2 < 4; ++r2) {
            float4 mm = *(const float4*)redbuf[0][16 * i + 4 * lg + r2];
            rowm[i][r2] = fmaxf(fmaxf(mm.x, mm.y), fmaxf(mm.z, mm.w));
        }
    float psum[2][4] = {};
#pragma unroll
    for (int i = 0; i < 2; ++i)
#pragma unroll
        for (int m = 0; m < 8; ++m)
#pragma unroll
            for (int r2 = 0; r2 < 4; ++r2) {
                float e = __expf(sc[i][m][r2] - rowm[i][r2]);
                sc[i][m][r2] = e;
                psum[i][r2] += e;
            }
#pragma unroll
    for (int i = 0; i < 2; ++i)
#pragma unroll
        for (int r2 = 0; r2 < 4; ++r2) {
            float s = psum[i][r2];
#pragma unroll
            for (int off = 1; off < 16; off <<= 1) s += __shfl_xor(s, off, 64);
            if (lr == 0) redbuf[1][16 * i + 4 * lg + r2][w] = s;
        }
    __syncthreads();
#pragma unroll
    for (int i = 0; i < 2; ++i)
#pragma unroll
        for (int r2 = 0; r2 < 4; ++r2) {
            float4 ss = *(const float4*)redbuf[1][16 * i + 4 * lg + r2];
            inv[i][r2] = 1.0f / (ss.x + ss.y + ss.z + ss.w);
        }

    // PV: staging buffers are per-wave-private -> wave-lockstep ordering,
    // no __syncthreads needed in this loop.
    f32x4 cacc[2][2] = {};
#pragma unroll
    for (int sh = 0; sh < 2; ++sh) {
#pragma unroll
        for (int mm2 = 0; mm2 < 4; ++mm2) {
            const int m = sh * 4 + mm2;
#pragma unroll
            for (int i = 0; i < 2; ++i)
#pragma unroll
                for (int r2 = 0; r2 < 4; ++r2) {
                    const int trow = 16 * i + 4 * lg + r2;
                    float a = sc[i][m][r2] * inv[i][r2];
                    unsigned short ah16 = f2bf(a);
                    unsigned short al16 = f2bf(a - bf2f(ah16));
                    const int cbyte = (mm2 * 16 + lr) * 2;
                    const int off = trow * 128 + (cbyte ^ ((trow & 7) << 4));
                    *(unsigned short*)(ubase + off) = ah16;
                    *(unsigned short*)(ubase + 4096 + off) = al16;
                }
        }
#pragma unroll
        for (int ks = 0; ks < 2; ++ks) {
            s16x8 pah[2], pal[2];
#pragma unroll
            for (int i = 0; i < 2; ++i) {
                const int trow = 16 * i + lr;
                const int cbyte = ks * 64 + lg * 16;
                const int off = trow * 128 + (cbyte ^ ((trow & 7) << 4));
                pah[i] = *(const s16x8*)(ubase + off);
                pal[i] = *(const s16x8*)(ubase + 4096 + off);
            }
#pragma unroll
            for (int n = 0; n < 2; ++n) {
                const int sg = w * 128 + sh * 64 + ks * 32 + lg * 8;
                const size_t vo = (bh * DHn + n * 16 + lr) * Tn + sg;
                s16x8 vh = *(const s16x8*)(vt_hi + vo);
                s16x8 vl = *(const s16x8*)(vt_lo + vo);
#pragma unroll
                for (int i = 0; i < 2; ++i)
                    cacc[i][n] = mfma3(pah[i], pal[i], vh, vl, cacc[i][n]);
            }
        }
    }

    // ctxred write is wave-private; single barrier before cross-wave read.
    {
        float* cr = (float*)ubase;
#pragma unroll
        for (int i = 0; i < 2; ++i)
#pragma unroll
            for (int n = 0; n < 2; ++n)
#pragma unroll
                for (int r2 = 0; r2 < 4; ++r2)
                    cr[(16 * i + 4 * lg + r2) * 36 + n * 16 + lr] = cacc[i][n][r2];
    }
    __syncthreads();
    {
        const int trow = tid >> 3, d0 = (tid & 7) * 4;
        float4 s0 = *(const float4*)((float*)uni[0] + trow * 36 + d0);
        float4 s1 = *(const float4*)((float*)uni[1] + trow * 36 + d0);
        float4 s2 = *(const float4*)((float*)uni[2] + trow * 36 + d0);
        float4 s3 = *(const float4*)((float*)uni[3] + trow * 36 + d0);
        float4 o = make_float4(s0.x + s1.x + s2.x + s3.x, s0.y + s1.y + s2.y + s3.y,
                               s0.z + s1.z + s2.z + s3.z, s0.w + s1.w + s2.w + s3.w);
        *(float4*)(ctx + ((size_t)b * Tn + t0 + trow) * Dn + h * DHn + d0) = o;
    }
}

// ---------------------------------------------------------------------------
extern "C" void kernel_launch(void* const* d_in, const int* in_sizes, int n_in,
                              void* d_out, int out_size, void* d_ws, size_t ws_size,
                              hipStream_t stream) {
    const float* query = (const float*)d_in[0];
    const float* key   = (const float*)d_in[1];
    const float* value = (const float*)d_in[2];
    const float* pos   = (const float*)d_in[3];
    const unsigned char* mask = (const unsigned char*)d_in[4];
    const float* bpp = (const float*)d_in[5];
    const float* Wq = (const float*)d_in[6];
    const float* bq = (const float*)d_in[7];
    const float* Wk = (const float*)d_in[8];
    const float* bk = (const float*)d_in[9];
    const float* Wv = (const float*)d_in[10];
    const float* bv = (const float*)d_in[11];
    const float* Wp = (const float*)d_in[12];
    const float* Wo = (const float*)d_in[13];
    const float* bo = (const float*)d_in[14];
    const float* ub = (const float*)d_in[15];
    const float* vbias = (const float*)d_in[16];
    const float* c1w = (const float*)d_in[17];
    const float* c1b = (const float*)d_in[18];
    const float* c2w = (const float*)d_in[19];
    const float* c2b = (const float*)d_in[20];

    char* wsb = (char*)d_ws;
    unsigned short* bias_ws = (unsigned short*)wsb;             // [B,T,T] bf16
    float* mask_ws = (float*)(wsb + sizeof(unsigned short) * (size_t)Bn * Tn * Tn);
    float* q_ws    = mask_ws + Bn * Tn;                          // [B,H,T,DH] f32
    float* ctx_ws  = q_ws + qkvE;                                // [B,T,D] f32
    unsigned short* k_hi = (unsigned short*)(ctx_ws + qkvE);
    unsigned short* k_lo = k_hi + qkvE;
    unsigned short* v_hi = k_lo + qkvE;                          // [B,H,DH,T]
    unsigned short* v_lo = v_hi + qkvE;
    unsigned short* p_hi = v_lo + qkvE;                          // [B,H,P,DH]
    unsigned short* p_lo = p_hi + posE;
    unsigned short* wall_hi = p_lo + posE;                       // 5 x [D,D]
    unsigned short* wall_lo = wall_hi + 5 * wE;

    // weight order: 0=Wq 1=Wk 2=Wv 3=Wp 4=Wo
    split_weights_kernel<<<dim3(64, 5), dim3(256), 0, stream>>>(
        Wq, Wk, Wv, Wp, Wo, wall_hi, wall_lo);

    phase1_kernel<<<dim3(2305), dim3(256), 0, stream>>>(
        query, key, value, pos, wall_hi, wall_lo, bq, bk, bv,
        q_ws, k_hi, k_lo, v_hi, v_lo, p_hi, p_lo,
        bpp, c1w, c1b, c2w, c2b, bias_ws, mask, mask_ws);

    attn_mfma_kernel<<<dim3(4096), dim3(256), 0, stream>>>(
        q_ws, k_hi, k_lo, v_hi, v_lo, p_hi, p_lo, bias_ws, mask_ws, ub, vbias, ctx_ws);

    gemm_o_kernel<<<dim3(512), dim3(256), 0, stream>>>(
        ctx_ws, wall_hi + 4 * wE, wall_lo + 4 * wE, bo, (float*)d_out);
}